// Round 4
// baseline (527.934 us; speedup 1.0000x reference)
//
#include <hip/hip_runtime.h>
#include <math.h>

#define KK 25      // KS*KS
#define H1C 32
#define H2C 64
#define FCC 128
#define NCLS 10
#define NG 64
#define M1 8       // nodes per block, layer-1 kernel
#define M2 8       // nodes per block, layer-2 kernel
#define SROW 804   // padded S row stride (800+4): row n starts at bank 4n%32
#define ECH 256    // staged edges per chunk (16B each -> 4KB LDS)

__device__ inline void fma4(float4& a, float s, const float4& w) {
    a.x = fmaf(s, w.x, a.x); a.y = fmaf(s, w.y, a.y);
    a.z = fmaf(s, w.z, a.z); a.w = fmaf(s, w.w, a.w);
}

// ---------------- degree + graph-count histograms ----------------
__global__ void deg_cnt_kernel(const int* __restrict__ edge_index, int E,
                               const int* __restrict__ batch, int N,
                               int* __restrict__ degi, float* __restrict__ cnt) {
    int i = blockIdx.x * blockDim.x + threadIdx.x;
    if (i < E) atomicAdd(&degi[edge_index[E + i]], 1);
    if (i < N) atomicAdd(&cnt[batch[i]], 1.0f);
}

// ---------------- prefix-sum (3-kernel) over degi -> rowst, cur ----------------
__global__ void scan1_kernel(const int* __restrict__ degi, int N,
                             int* __restrict__ incl, int* __restrict__ bsum) {
    __shared__ int s[256];
    int tid = threadIdx.x;
    int i = blockIdx.x * 256 + tid;
    int v = (i < N) ? degi[i] : 0;
    s[tid] = v;
    __syncthreads();
    for (int off = 1; off < 256; off <<= 1) {
        int t = (tid >= off) ? s[tid - off] : 0;
        __syncthreads();
        s[tid] += t;
        __syncthreads();
    }
    if (i < N) incl[i] = s[tid];
    if (tid == 255) bsum[blockIdx.x] = s[255];
}

__global__ void scan2_kernel(int* __restrict__ bsum, int nb) {
    __shared__ int s[256];
    int tid = threadIdx.x;
    int v = (tid < nb) ? bsum[tid] : 0;
    s[tid] = v;
    __syncthreads();
    for (int off = 1; off < 256; off <<= 1) {
        int t = (tid >= off) ? s[tid - off] : 0;
        __syncthreads();
        s[tid] += t;
        __syncthreads();
    }
    if (tid < nb) bsum[tid] = s[tid] - v;   // exclusive
}

__global__ void scan3_kernel(const int* __restrict__ incl, const int* __restrict__ degi,
                             const int* __restrict__ bsum, int N,
                             int* __restrict__ rowst, int* __restrict__ cur) {
    int i = blockIdx.x * 256 + threadIdx.x;
    if (i >= N) return;
    int r = incl[i] - degi[i] + bsum[blockIdx.x];
    rowst[i] = r;
    cur[i] = r;
}

// ---------------- bucket edges by dst, recomputing basis; 16B packed ----------
// packed edge: {src, kbase = k0+5*k1, bits(f0), bits(f1)}
__global__ void bucket_kernel(const float* __restrict__ edge_attr,
                              const int* __restrict__ edge_index, int E,
                              int* __restrict__ cur, int4* __restrict__ es) {
    int e = blockIdx.x * blockDim.x + threadIdx.x;
    if (e >= E) return;
    float v0 = edge_attr[2 * e + 0] * 4.0f;
    float v1 = edge_attr[2 * e + 1] * 4.0f;
    int k0 = (int)floorf(v0); k0 = min(max(k0, 0), 3);
    int k1 = (int)floorf(v1); k1 = min(max(k1, 0), 3);
    float f0 = v0 - (float)k0, f1 = v1 - (float)k1;
    int dst = edge_index[E + e];
    int pos = atomicAdd(&cur[dst], 1);
    es[pos] = make_int4(edge_index[e], k0 + 5 * k1,
                        __float_as_int(f0), __float_as_int(f1));
}

// ---------------- layer 1: CSR gather with LDS edge staging ----------------
// 256 threads = M1 nodes x 32 lanes(o)
__global__ __launch_bounds__(256) void l1_kernel(
    const float* __restrict__ x,
    const int* __restrict__ rowst, const int* __restrict__ degi,
    const int4* __restrict__ es,
    const float* __restrict__ W1, const float* __restrict__ root1,
    const float* __restrict__ b1, int N, int E, float* __restrict__ h1) {
    __shared__ float w1s[KK * H1C];
    __shared__ int4 ebuf[ECH];
    for (int i = threadIdx.x; i < KK * H1C; i += 256) w1s[i] = W1[i];
    int n0 = blockIdx.x * M1;
    int g = threadIdx.x >> 5, o = threadIdx.x & 31;
    int n = n0 + g;
    int myBeg = (n < N) ? rowst[n] : 0;
    int myCnt = (n < N) ? degi[n] : 0;
    int blkBeg = rowst[n0];
    int blkEnd = (n0 + M1 < N) ? rowst[n0 + M1] : E;
    float acc = 0.0f;
    for (int base = blkBeg; base < blkEnd; base += ECH) {
        int m = min(ECH, blkEnd - base);
        __syncthreads();
        for (int i = threadIdx.x; i < m; i += 256) ebuf[i] = es[base + i];
        __syncthreads();
        int lo = max(myBeg, base), hi = min(myBeg + myCnt, base + m);
        for (int e = lo; e < hi; e++) {
            int4 ed = ebuf[e - base];
            float f0 = __int_as_float(ed.z), f1 = __int_as_float(ed.w);
            float g0 = 1.0f - f0, g1 = 1.0f - f1;
            int kb = ed.y * H1C + o;
            float coef = g0 * g1 * w1s[kb] + g0 * f1 * w1s[kb + 5 * H1C] +
                         f0 * g1 * w1s[kb + H1C] + f0 * f1 * w1s[kb + 6 * H1C];
            acc = fmaf(x[ed.x], coef, acc);
        }
    }
    if (n < N) {
        float rdeg = 1.0f / fmaxf((float)myCnt, 1.0f);
        h1[n * H1C + o] = fmaxf(acc * rdeg + x[n] * root1[o] + b1[o], 0.0f);
    }
}

// ---------------- layer 2 fused: ds_add_f32 S-build + GEMM + epilogue + pool --
// 256 threads. Build: 8 groups x 32 lanes(c), 1 node each, LDS atomics.
// GEMM: thread = (kh 0..1) x (node 0..7) x (o4 0..15), k-split + LDS reduce.
__global__ __launch_bounds__(256) void l2_kernel(
    const float* __restrict__ h1,
    const int* __restrict__ rowst, const int* __restrict__ degi,
    const int4* __restrict__ es,
    const float* __restrict__ W2,     // [(k*32+c)*64+o]
    const float* __restrict__ root2,  // [c*64+o]
    const float* __restrict__ b2,
    const int* __restrict__ batch,
    int N, int E, float* __restrict__ gsum) {
    __shared__ float S[M2][SROW];     // 25.7 KB
    __shared__ int4 ebuf[ECH];        // 4 KB (also reduce buffer)
    int tid = threadIdx.x;
    int n0 = blockIdx.x * M2;
    for (int i = tid; i < M2 * SROW; i += 256) (&S[0][0])[i] = 0.0f;

    // ---- build phase
    {
        int g = tid >> 5, c = tid & 31;
        int n = n0 + g;
        int myBeg = (n < N) ? rowst[n] : 0;
        int myCnt = (n < N) ? degi[n] : 0;
        int blkBeg = rowst[n0];
        int blkEnd = (n0 + M2 < N) ? rowst[n0 + M2] : E;
        float* Sr = &S[g][0];
        for (int base = blkBeg; base < blkEnd; base += ECH) {
            int m = min(ECH, blkEnd - base);
            __syncthreads();          // guards S zero-init + previous ebuf reads
            for (int i = tid; i < m; i += 256) ebuf[i] = es[base + i];
            __syncthreads();
            int lo = max(myBeg, base), hi = min(myBeg + myCnt, base + m);
            for (int e = lo; e < hi; e++) {
                int4 ed = ebuf[e - base];
                float f0 = __int_as_float(ed.z), f1 = __int_as_float(ed.w);
                float g0 = 1.0f - f0, g1 = 1.0f - f1;
                int kb = ed.y * H1C + c;
                float h = h1[ed.x * H1C + c];
                atomicAdd(&Sr[kb],            g0 * g1 * h);   // ds_add_f32
                atomicAdd(&Sr[kb + 5 * H1C],  g0 * f1 * h);
                atomicAdd(&Sr[kb + H1C],      f0 * g1 * h);
                atomicAdd(&Sr[kb + 6 * H1C],  f0 * f1 * h);
            }
        }
    }
    __syncthreads();

    // ---- GEMM: acc[gn][o4*4..+3] = sum_kc S[gn][kc] * W2[kc*64 + o4*4..]
    int kh = tid >> 7;            // k-half
    int gn = (tid >> 4) & 7;      // node
    int o4 = tid & 15;
    const float4* Wv = (const float4*)W2;
    const float* Sr = &S[gn][0];
    float4 acc = make_float4(0, 0, 0, 0);
    for (int kc4 = kh * 100; kc4 < kh * 100 + 100; kc4++) {
        float4 sv = *(const float4*)&Sr[kc4 * 4];
        int kc = kc4 * 4;
        fma4(acc, sv.x, Wv[(kc + 0) * 16 + o4]);
        fma4(acc, sv.y, Wv[(kc + 1) * 16 + o4]);
        fma4(acc, sv.z, Wv[(kc + 2) * 16 + o4]);
        fma4(acc, sv.w, Wv[(kc + 3) * 16 + o4]);
    }
    float4* red = (float4*)ebuf;
    if (kh == 1) red[gn * 16 + o4] = acc;
    __syncthreads();              // also: all S reads complete after this

    // ---- epilogue (kh==0 threads): h2 = relu(acc/deg + h1@root2 + b2)
    float* h2buf = &S[0][0];      // reuse S as [M2][64]
    if (kh == 0) {
        float4 o2 = red[gn * 16 + o4];
        acc.x += o2.x; acc.y += o2.y; acc.z += o2.z; acc.w += o2.w;
        int nA = n0 + gn;
        float4 hv = make_float4(0, 0, 0, 0);
        if (nA < N) {
            float rd = 1.0f / fmaxf((float)degi[nA], 1.0f);
            float4 bb = *(const float4*)&b2[o4 * 4];
            hv = make_float4(acc.x * rd + bb.x, acc.y * rd + bb.y,
                             acc.z * rd + bb.z, acc.w * rd + bb.w);
            const float* hrow = h1 + nA * H1C;
#pragma unroll 8
            for (int c = 0; c < H1C; c++) {
                float4 rt = *(const float4*)&root2[c * H2C + o4 * 4];
                fma4(hv, hrow[c], rt);
            }
            hv.x = fmaxf(hv.x, 0.f); hv.y = fmaxf(hv.y, 0.f);
            hv.z = fmaxf(hv.z, 0.f); hv.w = fmaxf(hv.w, 0.f);
        }
        *(float4*)&h2buf[gn * H2C + o4 * 4] = hv;
    }
    __syncthreads();

    // ---- pool: block-local per-graph reduction, one atomic per (graph,o)
    if (tid < H2C) {
        int o = tid;
        float run = 0.0f;
        int curg = batch[n0];
        for (int ln = 0; ln < M2; ln++) {
            int n = n0 + ln;
            if (n >= N) break;
            int g = batch[n];
            if (g != curg) {
                atomicAdd(&gsum[curg * H2C + o], run);
                run = 0.0f;
                curg = g;
            }
            run += h2buf[ln * H2C + o];
        }
        atomicAdd(&gsum[curg * H2C + o], run);
    }
}

// ---------------- head: mean, FC1+relu, FC2, log_softmax ----------------
__global__ void head_kernel(const float* __restrict__ gsum, const float* __restrict__ cnt,
                            const float* __restrict__ Wf1, const float* __restrict__ bf1,
                            const float* __restrict__ Wf2, const float* __restrict__ bf2,
                            float* __restrict__ out) {
    __shared__ float gc[H2C];
    __shared__ float t1[FCC];
    __shared__ float lg[NCLS];
    __shared__ float lse;
    int g = blockIdx.x, tid = threadIdx.x;
    if (tid < H2C) gc[tid] = gsum[g * H2C + tid] / fmaxf(cnt[g], 1.0f);
    __syncthreads();
    {
        float acc = bf1[tid];
        for (int c = 0; c < H2C; c++) acc += gc[c] * Wf1[c * FCC + tid];
        t1[tid] = fmaxf(acc, 0.0f);
    }
    __syncthreads();
    if (tid < NCLS) {
        float acc = bf2[tid];
        for (int j = 0; j < FCC; j++) acc += t1[j] * Wf2[j * NCLS + tid];
        lg[tid] = acc;
    }
    __syncthreads();
    if (tid == 0) {
        float m = lg[0];
        for (int c = 1; c < NCLS; c++) m = fmaxf(m, lg[c]);
        float s = 0.0f;
        for (int c = 0; c < NCLS; c++) s += expf(lg[c] - m);
        lse = m + logf(s);
    }
    __syncthreads();
    if (tid < NCLS) out[g * NCLS + tid] = lg[tid] - lse;
}

extern "C" void kernel_launch(void* const* d_in, const int* in_sizes, int n_in,
                              void* d_out, int out_size, void* d_ws, size_t ws_size,
                              hipStream_t stream) {
    const float* x          = (const float*)d_in[0];
    const float* edge_attr  = (const float*)d_in[1];
    const float* W1         = (const float*)d_in[2];
    const float* root1      = (const float*)d_in[3];
    const float* b1         = (const float*)d_in[4];
    const float* W2         = (const float*)d_in[5];
    const float* root2      = (const float*)d_in[6];
    const float* b2         = (const float*)d_in[7];
    const float* Wf1        = (const float*)d_in[8];
    const float* bf1        = (const float*)d_in[9];
    const float* Wf2        = (const float*)d_in[10];
    const float* bf2        = (const float*)d_in[11];
    const int*   edge_index = (const int*)d_in[12];
    const int*   batch      = (const int*)d_in[13];
    float* out = (float*)d_out;

    const int N = in_sizes[13];       // 20000
    const int E = in_sizes[12] / 2;   // 320000
    const int NB = (N + 255) / 256;   // scan blocks (79)

    // -------- workspace layout --------
    int4*  es    = (int4*)d_ws;                      // E packed sorted edges
    float* gsum  = (float*)(es + E);                 // NG*H2C  -- zero block start
    float* cnt   = gsum + NG * H2C;                  // NG
    int*   degi  = (int*)(cnt + NG);                 // N       -- zero block end
    int*   rowst = degi + N;                         // N
    int*   cur   = rowst + N;                        // N
    int*   incl  = cur + N;                          // N
    int*   bsum  = incl + N;                         // 256
    float* h1    = (float*)(bsum + 256);             // N*H1C

    size_t zero_elems = (size_t)NG * H2C + NG + N;
    hipMemsetAsync(gsum, 0, zero_elems * sizeof(float), stream);

    deg_cnt_kernel<<<(E + 255) / 256, 256, 0, stream>>>(edge_index, E, batch, N, degi, cnt);

    scan1_kernel<<<NB, 256, 0, stream>>>(degi, N, incl, bsum);
    scan2_kernel<<<1, 256, 0, stream>>>(bsum, NB);
    scan3_kernel<<<NB, 256, 0, stream>>>(incl, degi, bsum, N, rowst, cur);

    bucket_kernel<<<(E + 255) / 256, 256, 0, stream>>>(edge_attr, edge_index, E, cur, es);

    l1_kernel<<<(N + M1 - 1) / M1, 256, 0, stream>>>(
        x, rowst, degi, es, W1, root1, b1, N, E, h1);

    l2_kernel<<<(N + M2 - 1) / M2, 256, 0, stream>>>(
        h1, rowst, degi, es, W2, root2, b2, batch, N, E, gsum);

    head_kernel<<<NG, FCC, 0, stream>>>(gsum, cnt, Wf1, bf1, Wf2, bf2, out);
}